// Round 4
// baseline (809.157 us; speedup 1.0000x reference)
//
#include <hip/hip_runtime.h>
#include <math.h>

#define N_NODES 50000
#define N_EDGES 800000
#define HID 64
#define N_GRAPHS 256
#define BN_EPS 1e-5f
#define GATE_EPS 1e-6f

static inline size_t align256(size_t x) { return (x + 255) & ~(size_t)255; }

// ---------------------------------------------------------------- utilities

__global__ void k_zero(int* __restrict__ p, int n) {
    for (int i = blockIdx.x * blockDim.x + threadIdx.x; i < n; i += gridDim.x * blockDim.x)
        p[i] = 0;
}

__global__ void k_deg(const int* __restrict__ dst, int* __restrict__ deg) {
    for (int i = blockIdx.x * blockDim.x + threadIdx.x; i < N_EDGES; i += gridDim.x * blockDim.x)
        atomicAdd(&deg[dst[i]], 1);
}

__global__ void k_norm(const int* __restrict__ deg, float* __restrict__ norm) {
    int i = blockIdx.x * blockDim.x + threadIdx.x;
    if (i < N_NODES) norm[i] = 1.0f / sqrtf(fmaxf((float)deg[i], 1.0f));
}

// exclusive scan of deg -> start (256/block, 2-level)
__global__ void k_scan1(const int* __restrict__ deg, int* __restrict__ start,
                        int* __restrict__ blksum) {
    __shared__ int s[256];
    int t = threadIdx.x;
    int i = blockIdx.x * 256 + t;
    int v = (i < N_NODES) ? deg[i] : 0;
    s[t] = v;
    __syncthreads();
    for (int off = 1; off < 256; off <<= 1) {
        int x = (t >= off) ? s[t - off] : 0;
        __syncthreads();
        s[t] += x;
        __syncthreads();
    }
    if (i < N_NODES) start[i] = s[t] - v;   // exclusive
    if (t == 255) blksum[blockIdx.x] = s[255];
}

__global__ void k_scan2(int* __restrict__ blksum, int nb) {
    __shared__ int s[256];
    int t = threadIdx.x;
    int v = (t < nb) ? blksum[t] : 0;
    s[t] = v;
    __syncthreads();
    for (int off = 1; off < 256; off <<= 1) {
        int x = (t >= off) ? s[t - off] : 0;
        __syncthreads();
        s[t] += x;
        __syncthreads();
    }
    if (t < nb) blksum[t] = s[t] - v;       // exclusive block offsets
}

__global__ void k_scan3(int* __restrict__ start, const int* __restrict__ blksum,
                        int* __restrict__ cursor) {
    int i = blockIdx.x * 256 + threadIdx.x;
    if (i < N_NODES) {
        int v = start[i] + blksum[blockIdx.x];
        start[i] = v;
        cursor[i] = v;
    }
    if (blockIdx.x == 0 && threadIdx.x == 0) start[N_NODES] = N_EDGES;
}

// scatter edges into dst-sorted order; pack src+etype, pre-gather norm[src]
__global__ void k_scatter(const int* __restrict__ dst, const int* __restrict__ src,
                          const int* __restrict__ etype, const float* __restrict__ norm,
                          int* __restrict__ cursor,
                          int* __restrict__ edge_pack, float* __restrict__ edge_norm) {
    for (int i = blockIdx.x * blockDim.x + threadIdx.x; i < N_EDGES; i += gridDim.x * blockDim.x) {
        int p = atomicAdd(&cursor[dst[i]], 1);
        int s = src[i];
        edge_pack[p] = s | (etype[i] << 24);
        edge_norm[p] = norm[s];
    }
}

// node encoder: hf[n] = node_emb[h[n]]  (float4-vectorized, 16B/lane)
__global__ __launch_bounds__(256) void k_embed(const int* __restrict__ h,
                                               const float* __restrict__ node_emb,
                                               float4* __restrict__ hf4) {
    const int total4 = N_NODES * (HID / 4);
    for (int i = blockIdx.x * blockDim.x + threadIdx.x; i < total4; i += gridDim.x * blockDim.x) {
        int n = i >> 4, c4 = i & 15;
        hf4[i] = ((const float4*)node_emb)[h[n] * (HID / 4) + c4];
    }
}

// ------------------------------------------------------- fused edge kernel
// One wave per node (lane == channel). ef is stored in dst-SORTED slot order
// (index j), so per-wave ef access is a sequential 256B-row stream.
//
// MODE 0 (layer 0): ef_prev = emb table; no BN-apply; no ef write.
// MODE 1 (layer 1): ef_prev = emb table; apply BN_e(0); first ef write.
// MODE 2 (layer 2): ef_prev = global ef;  apply BN_e(prev); ef write.
// MODE 3 (layer 3): ef_prev = global ef;  apply BN_e(prev); NO write (dead),
//                   and skip e-stats (dead).
//
// Inner loop is 1-deep software-pipelined: edge j+1's meta/gather/ef loads
// are issued before edge j's arithmetic consumes its loads, breaking the
// pack->decode->gather dependent chain (~200cy L2 latency per edge).
// Also computes h_new = (hf*norm + msg/(den+eps))*norm in-register and
// accumulates both BN stat sets.
template <int MODE>
__global__ __launch_bounds__(256) void k_edge(
    const int* __restrict__ start, const int* __restrict__ edge_pack,
    const float* __restrict__ edge_norm, const float* __restrict__ edge_emb,
    float* __restrict__ ef,
    const float* __restrict__ hf_old, const float* __restrict__ hf_new,
    const float* __restrict__ norm, float* __restrict__ h_new,
    const float* __restrict__ stats_prev, const float* __restrict__ gamma_prev,
    const float* __restrict__ beta_prev,
    float* __restrict__ stats_e_out, float* __restrict__ stats_h_out) {
    const int lane = threadIdx.x & 63;
    const int gw = blockIdx.x * (blockDim.x >> 6) + (threadIdx.x >> 6);
    const int nw = gridDim.x * (blockDim.x >> 6);

    __shared__ float s_emb[4 * HID];
    if (MODE <= 1) {
        for (int i = threadIdx.x; i < 4 * HID; i += blockDim.x) s_emb[i] = edge_emb[i];
        __syncthreads();
    }
    float a_prev = 0.f, c_prev = 0.f;
    if (MODE >= 1) {
        float s1 = stats_prev[lane], s2 = stats_prev[HID + lane];
        float mu = s1 * (1.0f / N_EDGES);
        float var = s2 * (1.0f / N_EDGES) - mu * mu;
        float rstd = 1.0f / sqrtf(var + BN_EPS);
        a_prev = gamma_prev[lane] * rstd;
        c_prev = beta_prev[lane] - mu * a_prev;
    }

    float sum_e = 0.f, sumsq_e = 0.f, sum_h = 0.f, sumsq_h = 0.f;
    for (int n = gw; n < N_NODES; n += nw) {
        const int jbeg = start[n], jend = start[n + 1];
        const float h_new_n = hf_new[n * HID + lane];
        const float h_old_n = (MODE >= 1) ? hf_old[n * HID + lane] : 0.f;
        float amsg = 0.f, aden = 0.f;
        if (jbeg < jend) {
            // ---- pipeline prologue: loads for edge jbeg
            int pk = edge_pack[jbeg];
            float ns = edge_norm[jbeg];
            int s = pk & 0xFFFFFF;
            float hs = hf_new[s * HID + lane];
            float ho = (MODE >= 1) ? hf_old[s * HID + lane] : 0.f;
            float efp = (MODE >= 2) ? ef[(size_t)jbeg * HID + lane] : 0.f;
            for (int j = jbeg; j < jend; ++j) {
                // ---- issue edge j+1's loads (clamped; all in-bounds)
                const int jn = (j + 1 < jend) ? j + 1 : jend - 1;
                const int pk_n = edge_pack[jn];
                const float ns_n = edge_norm[jn];
                const int s_n = pk_n & 0xFFFFFF;
                const float hs_n = hf_new[s_n * HID + lane];
                const float ho_n = (MODE >= 1) ? hf_old[s_n * HID + lane] : 0.f;
                const float efp_n = (MODE >= 2) ? ef[(size_t)jn * HID + lane] : 0.f;
                // ---- consume edge j
                float efv;
                if (MODE == 0) {
                    efv = s_emb[(pk >> 24) * HID + lane];
                } else if (MODE == 1) {
                    const float ef0 = s_emb[(pk >> 24) * HID + lane];
                    const float ep = ho + h_old_n + ef0;
                    efv = ef0 + fmaxf(a_prev * ep + c_prev, 0.f);
                    ef[(size_t)j * HID + lane] = efv;
                } else {
                    const float ep = ho + h_old_n + efp;
                    efv = efp + fmaxf(a_prev * ep + c_prev, 0.f);
                    if (MODE == 2) ef[(size_t)j * HID + lane] = efv;
                }
                const float en = hs + h_new_n + efv;
                const float sg = 1.0f / (1.0f + __expf(-en));
                amsg += sg * hs * ns;
                aden += sg;
                if (MODE != 3) { sum_e += en; sumsq_e += en * en; }
                // ---- rotate pipeline
                pk = pk_n; ns = ns_n; s = s_n; hs = hs_n; ho = ho_n; efp = efp_n;
            }
        }
        const float nm = norm[n];
        const float hval = (h_new_n * nm + amsg / (aden + GATE_EPS)) * nm;
        h_new[n * HID + lane] = hval;
        sum_h += hval;
        sumsq_h += hval * hval;
    }

    __shared__ float sred[4][256];
    sred[0][threadIdx.x] = sum_e;
    sred[1][threadIdx.x] = sumsq_e;
    sred[2][threadIdx.x] = sum_h;
    sred[3][threadIdx.x] = sumsq_h;
    __syncthreads();
    if (threadIdx.x < 64) {
        const int t = threadIdx.x;
        if (MODE != 3) {
            float t1 = sred[0][t] + sred[0][t + 64] + sred[0][t + 128] + sred[0][t + 192];
            float t2 = sred[1][t] + sred[1][t + 64] + sred[1][t + 128] + sred[1][t + 192];
            atomicAdd(&stats_e_out[t], t1);
            atomicAdd(&stats_e_out[HID + t], t2);
        }
        float t3 = sred[2][t] + sred[2][t + 64] + sred[2][t + 128] + sred[2][t + 192];
        float t4 = sred[3][t] + sred[3][t + 64] + sred[3][t + 128] + sred[3][t + 192];
        atomicAdd(&stats_h_out[t], t3);
        atomicAdd(&stats_h_out[HID + t], t4);
    }
}

// ------------------------------------------------------------- node update
// hf_out = hf_in + relu(bn_h(h_new)), float4-vectorized (16B/lane).
// Grid-stride is a multiple of 16 float4s, so (i&15) is loop-invariant:
// BN coefficients hoist to 4 registers per thread.
__global__ __launch_bounds__(256) void k_hupd(
    const float4* __restrict__ hf_in, const float4* __restrict__ h_new,
    const float* __restrict__ stats, const float* __restrict__ gamma,
    const float* __restrict__ beta, float4* __restrict__ hf_out) {
    const int tid = blockIdx.x * blockDim.x + threadIdx.x;
    const int c0 = (tid & 15) * 4;
    float a[4], c[4];
#pragma unroll
    for (int k = 0; k < 4; ++k) {
        int ch = c0 + k;
        float mu = stats[ch] * (1.0f / N_NODES);
        float var = stats[HID + ch] * (1.0f / N_NODES) - mu * mu;
        float rstd = 1.0f / sqrtf(var + BN_EPS);
        a[k] = gamma[ch] * rstd;
        c[k] = beta[ch] - mu * a[k];
    }
    const int total4 = N_NODES * (HID / 4);
    for (int i = tid; i < total4; i += gridDim.x * blockDim.x) {
        float4 hi = hf_in[i], hn = h_new[i], o;
        o.x = hi.x + fmaxf(a[0] * hn.x + c[0], 0.f);
        o.y = hi.y + fmaxf(a[1] * hn.y + c[1], 0.f);
        o.z = hi.z + fmaxf(a[2] * hn.z + c[2], 0.f);
        o.w = hi.w + fmaxf(a[3] * hn.w + c[3], 0.f);
        hf_out[i] = o;
    }
}

// --------------------------------------------- fused mean-pool + MLP head
// graph_ids is sorted: one block per graph, binary-search the node range.
__global__ __launch_bounds__(256) void k_poolmlp(
    const float* __restrict__ hf, const int* __restrict__ graph_ids,
    const float* __restrict__ W1, const float* __restrict__ b1,
    const float* __restrict__ W2, const float* __restrict__ b2,
    const float* __restrict__ W3, const float* __restrict__ b3,
    float* __restrict__ out) {
    const int g = blockIdx.x;
    int a = 0, b = N_NODES;
    while (a < b) { int m = (a + b) >> 1; if (graph_ids[m] < g) a = m + 1; else b = m; }
    const int lo = a;
    b = N_NODES;
    while (a < b) { int m = (a + b) >> 1; if (graph_ids[m] < g + 1) a = m + 1; else b = m; }
    const int hi = a;

    const int lane = threadIdx.x & 63, w = threadIdx.x >> 6;
    float acc = 0.f;
    for (int n = lo + w; n < hi; n += 4) acc += hf[n * HID + lane];
    __shared__ float sred[256];
    __shared__ float sh[64], sx1[32], sx2[16];
    sred[threadIdx.x] = acc;
    __syncthreads();
    if (threadIdx.x < 64) {
        float tot = sred[lane] + sred[lane + 64] + sred[lane + 128] + sred[lane + 192];
        sh[lane] = tot / fmaxf((float)(hi - lo), 1.0f);
    }
    __syncthreads();
    const int t = threadIdx.x;
    if (t < 32) {
        float s = b1[t];
        for (int c = 0; c < 64; ++c) s += sh[c] * W1[c * 32 + t];
        sx1[t] = fmaxf(s, 0.f);
    }
    __syncthreads();
    if (t < 16) {
        float s = b2[t];
        for (int k = 0; k < 32; ++k) s += sx1[k] * W2[k * 16 + t];
        sx2[t] = fmaxf(s, 0.f);
    }
    __syncthreads();
    if (t == 0) {
        float s = b3[0];
        for (int k = 0; k < 16; ++k) s += sx2[k] * W3[k];
        out[g] = s;
    }
}

// -------------------------------------------------------------------- launch

extern "C" void kernel_launch(void* const* d_in, const int* in_sizes, int n_in,
                              void* d_out, int out_size, void* d_ws, size_t ws_size,
                              hipStream_t stream) {
    const int* h_idx      = (const int*)d_in[0];
    const int* e_idx      = (const int*)d_in[1];
    const int* src        = (const int*)d_in[2];
    const int* dst        = (const int*)d_in[3];
    const int* graph_ids  = (const int*)d_in[4];
    const float* node_emb = (const float*)d_in[5];
    const float* edge_emb = (const float*)d_in[6];
    const float* bnh_g    = (const float*)d_in[7];
    const float* bnh_b    = (const float*)d_in[8];
    const float* bne_g    = (const float*)d_in[9];
    const float* bne_b    = (const float*)d_in[10];
    const float* W1       = (const float*)d_in[11];
    const float* b1       = (const float*)d_in[12];
    const float* W2       = (const float*)d_in[13];
    const float* b2       = (const float*)d_in[14];
    const float* W3       = (const float*)d_in[15];
    const float* b3       = (const float*)d_in[16];
    float* out = (float*)d_out;

    // ---- workspace layout (~262 MB)
    char* w = (char*)d_ws;
    size_t off = 0;
    auto alloc = [&](size_t bytes) -> void* {
        void* p = w + off;
        off = align256(off + bytes);
        return p;
    };
    float* ef        = (float*)alloc((size_t)N_EDGES * HID * 4);   // sorted-slot order
    float* hfA       = (float*)alloc((size_t)N_NODES * HID * 4);
    float* hfB       = (float*)alloc((size_t)N_NODES * HID * 4);
    float* h_new     = (float*)alloc((size_t)N_NODES * HID * 4);
    float* norm      = (float*)alloc((size_t)N_NODES * 4);
    int*   edge_pack = (int*)alloc((size_t)N_EDGES * 4);
    float* edge_norm = (float*)alloc((size_t)N_EDGES * 4);
    int*   start     = (int*)alloc((size_t)(N_NODES + 1) * 4);
    int*   cursor    = (int*)alloc((size_t)N_NODES * 4);
    int*   blksum    = (int*)alloc(256 * 4);
    // zero-initialized region (contiguous)
    size_t zoff = off;
    int*   deg       = (int*)alloc((size_t)N_NODES * 4);
    float* stats_e   = (float*)alloc(4 * 2 * HID * 4);
    float* stats_h   = (float*)alloc(4 * 2 * HID * 4);
    int zero_elems = (int)((off - zoff) / 4);
    int* zbase = (int*)(w + zoff);

    const int NB_SCAN = (N_NODES + 255) / 256;   // 196

    // ---- preprocessing
    k_zero<<<64, 256, 0, stream>>>(zbase, zero_elems);
    k_deg<<<1024, 256, 0, stream>>>(dst, deg);
    k_norm<<<NB_SCAN, 256, 0, stream>>>(deg, norm);
    k_scan1<<<NB_SCAN, 256, 0, stream>>>(deg, start, blksum);
    k_scan2<<<1, 256, 0, stream>>>(blksum, NB_SCAN);
    k_scan3<<<NB_SCAN, 256, 0, stream>>>(start, blksum, cursor);
    k_scatter<<<1024, 256, 0, stream>>>(dst, src, e_idx, norm, cursor, edge_pack, edge_norm);
    k_embed<<<512, 256, 0, stream>>>(h_idx, node_emb, (float4*)hfA);

    const int EG = 2048;   // edge-kernel blocks (8192 waves, ~6 nodes/wave)
    const int NG = 512;    // node-kernel blocks

    // ---- layer 0 (ef_prev from emb table, no BN-apply)
    k_edge<0><<<EG, 256, 0, stream>>>(start, edge_pack, edge_norm, edge_emb, ef,
        nullptr, hfA, norm, h_new, nullptr, nullptr, nullptr,
        stats_e + 0 * 128, stats_h + 0 * 128);
    k_hupd<<<NG, 256, 0, stream>>>((const float4*)hfA, (const float4*)h_new,
        stats_h + 0 * 128, bnh_g + 0 * HID, bnh_b + 0 * HID, (float4*)hfB);

    // ---- layer 1 (ef_prev from emb table; apply BN_e(0); first ef write)
    k_edge<1><<<EG, 256, 0, stream>>>(start, edge_pack, edge_norm, edge_emb, ef,
        hfA, hfB, norm, h_new, stats_e + 0 * 128, bne_g + 0 * HID, bne_b + 0 * HID,
        stats_e + 1 * 128, stats_h + 1 * 128);
    k_hupd<<<NG, 256, 0, stream>>>((const float4*)hfB, (const float4*)h_new,
        stats_h + 1 * 128, bnh_g + 1 * HID, bnh_b + 1 * HID, (float4*)hfA);

    // ---- layer 2 (ef read+write)
    k_edge<2><<<EG, 256, 0, stream>>>(start, edge_pack, edge_norm, edge_emb, ef,
        hfB, hfA, norm, h_new, stats_e + 1 * 128, bne_g + 1 * HID, bne_b + 1 * HID,
        stats_e + 2 * 128, stats_h + 2 * 128);
    k_hupd<<<NG, 256, 0, stream>>>((const float4*)hfA, (const float4*)h_new,
        stats_h + 2 * 128, bnh_g + 2 * HID, bnh_b + 2 * HID, (float4*)hfB);

    // ---- layer 3 (ef read only; e-side outputs dead)
    k_edge<3><<<EG, 256, 0, stream>>>(start, edge_pack, edge_norm, edge_emb, ef,
        hfA, hfB, norm, h_new, stats_e + 2 * 128, bne_g + 2 * HID, bne_b + 2 * HID,
        stats_e + 3 * 128, stats_h + 3 * 128);
    k_hupd<<<NG, 256, 0, stream>>>((const float4*)hfB, (const float4*)h_new,
        stats_h + 3 * 128, bnh_g + 3 * HID, bnh_b + 3 * HID, (float4*)hfA);

    // ---- fused mean-pool + MLP readout
    k_poolmlp<<<N_GRAPHS, 256, 0, stream>>>(hfA, graph_ids, W1, b1, W2, b2, W3, b3, out);
}

// Round 6
// 773.648 us; speedup vs baseline: 1.0459x; 1.0459x over previous
//
#include <hip/hip_runtime.h>
#include <math.h>

#define N_NODES 50000
#define N_EDGES 800000
#define HID 64
#define N_GRAPHS 256
#define BN_EPS 1e-5f
#define GATE_EPS 1e-6f

static inline size_t align256(size_t x) { return (x + 255) & ~(size_t)255; }

// ---------------------------------------------------------------- utilities

__global__ void k_zero(int* __restrict__ p, int n) {
    for (int i = blockIdx.x * blockDim.x + threadIdx.x; i < n; i += gridDim.x * blockDim.x)
        p[i] = 0;
}

__global__ void k_deg(const int* __restrict__ dst, int* __restrict__ deg) {
    for (int i = blockIdx.x * blockDim.x + threadIdx.x; i < N_EDGES; i += gridDim.x * blockDim.x)
        atomicAdd(&deg[dst[i]], 1);
}

__global__ void k_norm(const int* __restrict__ deg, float* __restrict__ norm) {
    int i = blockIdx.x * blockDim.x + threadIdx.x;
    if (i < N_NODES) norm[i] = 1.0f / sqrtf(fmaxf((float)deg[i], 1.0f));
}

// exclusive scan of deg -> start (256/block, 2-level)
__global__ void k_scan1(const int* __restrict__ deg, int* __restrict__ start,
                        int* __restrict__ blksum) {
    __shared__ int s[256];
    int t = threadIdx.x;
    int i = blockIdx.x * 256 + t;
    int v = (i < N_NODES) ? deg[i] : 0;
    s[t] = v;
    __syncthreads();
    for (int off = 1; off < 256; off <<= 1) {
        int x = (t >= off) ? s[t - off] : 0;
        __syncthreads();
        s[t] += x;
        __syncthreads();
    }
    if (i < N_NODES) start[i] = s[t] - v;   // exclusive
    if (t == 255) blksum[blockIdx.x] = s[255];
}

__global__ void k_scan2(int* __restrict__ blksum, int nb) {
    __shared__ int s[256];
    int t = threadIdx.x;
    int v = (t < nb) ? blksum[t] : 0;
    s[t] = v;
    __syncthreads();
    for (int off = 1; off < 256; off <<= 1) {
        int x = (t >= off) ? s[t - off] : 0;
        __syncthreads();
        s[t] += x;
        __syncthreads();
    }
    if (t < nb) blksum[t] = s[t] - v;       // exclusive block offsets
}

__global__ void k_scan3(int* __restrict__ start, const int* __restrict__ blksum,
                        int* __restrict__ cursor) {
    int i = blockIdx.x * 256 + threadIdx.x;
    if (i < N_NODES) {
        int v = start[i] + blksum[blockIdx.x];
        start[i] = v;
        cursor[i] = v;
    }
    if (blockIdx.x == 0 && threadIdx.x == 0) start[N_NODES] = N_EDGES;
}

// scatter edges into dst-sorted order; meta = {src|etype<<24, norm[src] bits}
__global__ void k_scatter(const int* __restrict__ dst, const int* __restrict__ src,
                          const int* __restrict__ etype, const float* __restrict__ norm,
                          int* __restrict__ cursor, int2* __restrict__ edge_meta) {
    for (int i = blockIdx.x * blockDim.x + threadIdx.x; i < N_EDGES; i += gridDim.x * blockDim.x) {
        int p = atomicAdd(&cursor[dst[i]], 1);
        int s = src[i];
        edge_meta[p] = make_int2(s | (etype[i] << 24), __float_as_int(norm[s]));
    }
}

// node encoder: hf[n] = node_emb[h[n]]  (float4-vectorized, 16B/lane)
__global__ __launch_bounds__(256) void k_embed(const int* __restrict__ h,
                                               const float* __restrict__ node_emb,
                                               float4* __restrict__ hf4) {
    const int total4 = N_NODES * (HID / 4);
    for (int i = blockIdx.x * blockDim.x + threadIdx.x; i < total4; i += gridDim.x * blockDim.x) {
        int n = i >> 4, c4 = i & 15;
        hf4[i] = ((const float4*)node_emb)[h[n] * (HID / 4) + c4];
    }
}

// ------------------------------------------------------- fused edge kernel
// One wave per 4 NODES (lane == channel), 4 independent edge streams
// interleaved for 4x memory-level parallelism (r4 PMC: 41% HBM, 38% VALU,
// VGPR=20 -> latency-bound with huge register headroom).
// 50000 nodes = 3125 blocks x 4 waves x 4 nodes exactly (no tail).
// ef is stored in dst-SORTED slot order (index j): sequential row stream.
//
// MODE 0 (layer 0): ef_prev = emb table; no BN-apply; no ef write.
// MODE 1 (layer 1): ef_prev = emb table; apply BN_e(0); first ef write.
// MODE 2 (layer 2): ef_prev = global ef;  apply BN_e(prev); ef write.
// MODE 3 (layer 3): ef_prev = global ef;  apply BN_e(prev); NO write, no e-stats.
//
// All stream bookkeeping is wave-uniform (start[n0+k] is lane-invariant), so
// per-lane predication never diverges. Exhausted streams clamp their index
// (cache-hot re-reads) with stores/accumulation predicated off.
template <int MODE>
__global__ __launch_bounds__(256) void k_edge(
    const int* __restrict__ start, const int2* __restrict__ edge_meta,
    const float* __restrict__ edge_emb,
    float* __restrict__ ef,
    const float* __restrict__ hf_old, const float* __restrict__ hf_new,
    const float* __restrict__ norm, float* __restrict__ h_new,
    const float* __restrict__ stats_prev, const float* __restrict__ gamma_prev,
    const float* __restrict__ beta_prev,
    float* __restrict__ stats_e_out, float* __restrict__ stats_h_out) {
    const int lane = threadIdx.x & 63;
    const int wid = __builtin_amdgcn_readfirstlane(blockIdx.x * 4 + (threadIdx.x >> 6));
    const int n0 = wid * 4;   // this wave's 4 consecutive nodes

    __shared__ float s_emb[4 * HID];
    if (MODE <= 1) {
        for (int i = threadIdx.x; i < 4 * HID; i += blockDim.x) s_emb[i] = edge_emb[i];
        __syncthreads();
    }
    float a_prev = 0.f, c_prev = 0.f;
    if (MODE >= 1) {
        float s1 = stats_prev[lane], s2 = stats_prev[HID + lane];
        float mu = s1 * (1.0f / N_EDGES);
        float var = s2 * (1.0f / N_EDGES) - mu * mu;
        float rstd = 1.0f / sqrtf(var + BN_EPS);
        a_prev = gamma_prev[lane] * rstd;
        c_prev = beta_prev[lane] - mu * a_prev;
    }

    // per-stream setup (k fully unrolled -> static indexing, regs not scratch)
    int jbeg[4], len[4];
    float hnn[4], hon[4], amsg[4], aden[4];
    int maxlen = 0;
#pragma unroll
    for (int k = 0; k < 4; ++k) {
        jbeg[k] = start[n0 + k];
        len[k] = start[n0 + k + 1] - jbeg[k];
        maxlen = max(maxlen, len[k]);
        hnn[k] = hf_new[(n0 + k) * HID + lane];
        hon[k] = (MODE >= 1) ? hf_old[(n0 + k) * HID + lane] : 0.f;
        amsg[k] = 0.f;
        aden[k] = 0.f;
    }

    float sum_e = 0.f, sumsq_e = 0.f, sum_h = 0.f, sumsq_h = 0.f;
    for (int it = 0; it < maxlen; ++it) {
#pragma unroll
        for (int k = 0; k < 4; ++k) {
            const bool act = it < len[k];                      // wave-uniform
            int jc = jbeg[k] + (act ? it : max(len[k] - 1, 0));
            jc = min(jc, N_EDGES - 1);
            const int2 mt = edge_meta[jc];
            const int s = mt.x & 0xFFFFFF;
            const float ns = __int_as_float(mt.y);
            float efv;
            if (MODE == 0) {
                efv = s_emb[(mt.x >> 24) * HID + lane];
            } else if (MODE == 1) {
                const float ef0 = s_emb[(mt.x >> 24) * HID + lane];
                const float ep = hf_old[s * HID + lane] + hon[k] + ef0;
                efv = ef0 + fmaxf(a_prev * ep + c_prev, 0.f);
                if (act) ef[(size_t)jc * HID + lane] = efv;
            } else {
                const float efp = ef[(size_t)jc * HID + lane];
                const float ep = hf_old[s * HID + lane] + hon[k] + efp;
                efv = efp + fmaxf(a_prev * ep + c_prev, 0.f);
                if (MODE == 2) { if (act) ef[(size_t)jc * HID + lane] = efv; }
            }
            const float hs = hf_new[s * HID + lane];
            const float en = hs + hnn[k] + efv;
            const float sg = 1.0f / (1.0f + __expf(-en));
            if (act) {
                amsg[k] += sg * hs * ns;
                aden[k] += sg;
                if (MODE != 3) { sum_e += en; sumsq_e += en * en; }
            }
        }
    }

#pragma unroll
    for (int k = 0; k < 4; ++k) {
        const float nm = norm[n0 + k];
        const float hval = (hnn[k] * nm + amsg[k] / (aden[k] + GATE_EPS)) * nm;
        h_new[(n0 + k) * HID + lane] = hval;
        sum_h += hval;
        sumsq_h += hval * hval;
    }

    __shared__ float sred[4][256];
    sred[0][threadIdx.x] = sum_e;
    sred[1][threadIdx.x] = sumsq_e;
    sred[2][threadIdx.x] = sum_h;
    sred[3][threadIdx.x] = sumsq_h;
    __syncthreads();
    if (threadIdx.x < 64) {
        const int t = threadIdx.x;
        if (MODE != 3) {
            float t1 = sred[0][t] + sred[0][t + 64] + sred[0][t + 128] + sred[0][t + 192];
            float t2 = sred[1][t] + sred[1][t + 64] + sred[1][t + 128] + sred[1][t + 192];
            atomicAdd(&stats_e_out[t], t1);
            atomicAdd(&stats_e_out[HID + t], t2);
        }
        float t3 = sred[2][t] + sred[2][t + 64] + sred[2][t + 128] + sred[2][t + 192];
        float t4 = sred[3][t] + sred[3][t + 64] + sred[3][t + 128] + sred[3][t + 192];
        atomicAdd(&stats_h_out[t], t3);
        atomicAdd(&stats_h_out[HID + t], t4);
    }
}

// ------------------------------------------------------------- node update
// hf_out = hf_in + relu(bn_h(h_new)), float4-vectorized (16B/lane).
__global__ __launch_bounds__(256) void k_hupd(
    const float4* __restrict__ hf_in, const float4* __restrict__ h_new,
    const float* __restrict__ stats, const float* __restrict__ gamma,
    const float* __restrict__ beta, float4* __restrict__ hf_out) {
    const int tid = blockIdx.x * blockDim.x + threadIdx.x;
    const int c0 = (tid & 15) * 4;
    float a[4], c[4];
#pragma unroll
    for (int k = 0; k < 4; ++k) {
        int ch = c0 + k;
        float mu = stats[ch] * (1.0f / N_NODES);
        float var = stats[HID + ch] * (1.0f / N_NODES) - mu * mu;
        float rstd = 1.0f / sqrtf(var + BN_EPS);
        a[k] = gamma[ch] * rstd;
        c[k] = beta[ch] - mu * a[k];
    }
    const int total4 = N_NODES * (HID / 4);
    for (int i = tid; i < total4; i += gridDim.x * blockDim.x) {
        float4 hi = hf_in[i], hn = h_new[i], o;
        o.x = hi.x + fmaxf(a[0] * hn.x + c[0], 0.f);
        o.y = hi.y + fmaxf(a[1] * hn.y + c[1], 0.f);
        o.z = hi.z + fmaxf(a[2] * hn.z + c[2], 0.f);
        o.w = hi.w + fmaxf(a[3] * hn.w + c[3], 0.f);
        hf_out[i] = o;
    }
}

// --------------------------------------------- fused mean-pool + MLP head
// graph_ids is sorted: one block per graph, binary-search the node range.
__global__ __launch_bounds__(256) void k_poolmlp(
    const float* __restrict__ hf, const int* __restrict__ graph_ids,
    const float* __restrict__ W1, const float* __restrict__ b1,
    const float* __restrict__ W2, const float* __restrict__ b2,
    const float* __restrict__ W3, const float* __restrict__ b3,
    float* __restrict__ out) {
    const int g = blockIdx.x;
    int a = 0, b = N_NODES;
    while (a < b) { int m = (a + b) >> 1; if (graph_ids[m] < g) a = m + 1; else b = m; }
    const int lo = a;
    b = N_NODES;
    while (a < b) { int m = (a + b) >> 1; if (graph_ids[m] < g + 1) a = m + 1; else b = m; }
    const int hi = a;

    const int lane = threadIdx.x & 63, w = threadIdx.x >> 6;
    float acc = 0.f;
    for (int n = lo + w; n < hi; n += 4) acc += hf[n * HID + lane];
    __shared__ float sred[256];
    __shared__ float sh[64], sx1[32], sx2[16];
    sred[threadIdx.x] = acc;
    __syncthreads();
    if (threadIdx.x < 64) {
        float tot = sred[lane] + sred[lane + 64] + sred[lane + 128] + sred[lane + 192];
        sh[lane] = tot / fmaxf((float)(hi - lo), 1.0f);
    }
    __syncthreads();
    const int t = threadIdx.x;
    if (t < 32) {
        float s = b1[t];
        for (int c = 0; c < 64; ++c) s += sh[c] * W1[c * 32 + t];
        sx1[t] = fmaxf(s, 0.f);
    }
    __syncthreads();
    if (t < 16) {
        float s = b2[t];
        for (int k = 0; k < 32; ++k) s += sx1[k] * W2[k * 16 + t];
        sx2[t] = fmaxf(s, 0.f);
    }
    __syncthreads();
    if (t == 0) {
        float s = b3[0];
        for (int k = 0; k < 16; ++k) s += sx2[k] * W3[k];
        out[g] = s;
    }
}

// -------------------------------------------------------------------- launch

extern "C" void kernel_launch(void* const* d_in, const int* in_sizes, int n_in,
                              void* d_out, int out_size, void* d_ws, size_t ws_size,
                              hipStream_t stream) {
    const int* h_idx      = (const int*)d_in[0];
    const int* e_idx      = (const int*)d_in[1];
    const int* src        = (const int*)d_in[2];
    const int* dst        = (const int*)d_in[3];
    const int* graph_ids  = (const int*)d_in[4];
    const float* node_emb = (const float*)d_in[5];
    const float* edge_emb = (const float*)d_in[6];
    const float* bnh_g    = (const float*)d_in[7];
    const float* bnh_b    = (const float*)d_in[8];
    const float* bne_g    = (const float*)d_in[9];
    const float* bne_b    = (const float*)d_in[10];
    const float* W1       = (const float*)d_in[11];
    const float* b1       = (const float*)d_in[12];
    const float* W2       = (const float*)d_in[13];
    const float* b2       = (const float*)d_in[14];
    const float* W3       = (const float*)d_in[15];
    const float* b3       = (const float*)d_in[16];
    float* out = (float*)d_out;

    // ---- workspace layout (~262 MB)
    char* w = (char*)d_ws;
    size_t off = 0;
    auto alloc = [&](size_t bytes) -> void* {
        void* p = w + off;
        off = align256(off + bytes);
        return p;
    };
    float* ef        = (float*)alloc((size_t)N_EDGES * HID * 4);   // sorted-slot order
    float* hfA       = (float*)alloc((size_t)N_NODES * HID * 4);
    float* hfB       = (float*)alloc((size_t)N_NODES * HID * 4);
    float* h_new     = (float*)alloc((size_t)N_NODES * HID * 4);
    float* norm      = (float*)alloc((size_t)N_NODES * 4);
    int2*  edge_meta = (int2*)alloc((size_t)N_EDGES * 8);
    int*   start     = (int*)alloc((size_t)(N_NODES + 1) * 4);
    int*   cursor    = (int*)alloc((size_t)N_NODES * 4);
    int*   blksum    = (int*)alloc(256 * 4);
    // zero-initialized region (contiguous)
    size_t zoff = off;
    int*   deg       = (int*)alloc((size_t)N_NODES * 4);
    float* stats_e   = (float*)alloc(4 * 2 * HID * 4);
    float* stats_h   = (float*)alloc(4 * 2 * HID * 4);
    int zero_elems = (int)((off - zoff) / 4);
    int* zbase = (int*)(w + zoff);

    const int NB_SCAN = (N_NODES + 255) / 256;   // 196

    // ---- preprocessing
    k_zero<<<64, 256, 0, stream>>>(zbase, zero_elems);
    k_deg<<<1024, 256, 0, stream>>>(dst, deg);
    k_norm<<<NB_SCAN, 256, 0, stream>>>(deg, norm);
    k_scan1<<<NB_SCAN, 256, 0, stream>>>(deg, start, blksum);
    k_scan2<<<1, 256, 0, stream>>>(blksum, NB_SCAN);
    k_scan3<<<NB_SCAN, 256, 0, stream>>>(start, blksum, cursor);
    k_scatter<<<1024, 256, 0, stream>>>(dst, src, e_idx, norm, cursor, edge_meta);
    k_embed<<<512, 256, 0, stream>>>(h_idx, node_emb, (float4*)hfA);

    const int EG = N_NODES / 16;   // 3125 blocks: 4 waves x 4 nodes each, exact
    const int NG = 512;            // node-kernel blocks

    // ---- layer 0 (ef_prev from emb table, no BN-apply)
    k_edge<0><<<EG, 256, 0, stream>>>(start, edge_meta, edge_emb, ef,
        nullptr, hfA, norm, h_new, nullptr, nullptr, nullptr,
        stats_e + 0 * 128, stats_h + 0 * 128);
    k_hupd<<<NG, 256, 0, stream>>>((const float4*)hfA, (const float4*)h_new,
        stats_h + 0 * 128, bnh_g + 0 * HID, bnh_b + 0 * HID, (float4*)hfB);

    // ---- layer 1 (ef_prev from emb table; apply BN_e(0); first ef write)
    k_edge<1><<<EG, 256, 0, stream>>>(start, edge_meta, edge_emb, ef,
        hfA, hfB, norm, h_new, stats_e + 0 * 128, bne_g + 0 * HID, bne_b + 0 * HID,
        stats_e + 1 * 128, stats_h + 1 * 128);
    k_hupd<<<NG, 256, 0, stream>>>((const float4*)hfB, (const float4*)h_new,
        stats_h + 1 * 128, bnh_g + 1 * HID, bnh_b + 1 * HID, (float4*)hfA);

    // ---- layer 2 (ef read+write)
    k_edge<2><<<EG, 256, 0, stream>>>(start, edge_meta, edge_emb, ef,
        hfB, hfA, norm, h_new, stats_e + 1 * 128, bne_g + 1 * HID, bne_b + 1 * HID,
        stats_e + 2 * 128, stats_h + 2 * 128);
    k_hupd<<<NG, 256, 0, stream>>>((const float4*)hfA, (const float4*)h_new,
        stats_h + 2 * 128, bnh_g + 2 * HID, bnh_b + 2 * HID, (float4*)hfB);

    // ---- layer 3 (ef read only; e-side outputs dead)
    k_edge<3><<<EG, 256, 0, stream>>>(start, edge_meta, edge_emb, ef,
        hfA, hfB, norm, h_new, stats_e + 2 * 128, bne_g + 2 * HID, bne_b + 2 * HID,
        stats_e + 3 * 128, stats_h + 3 * 128);
    k_hupd<<<NG, 256, 0, stream>>>((const float4*)hfB, (const float4*)h_new,
        stats_h + 3 * 128, bnh_g + 3 * HID, bnh_b + 3 * HID, (float4*)hfA);

    // ---- fused mean-pool + MLP readout
    k_poolmlp<<<N_GRAPHS, 256, 0, stream>>>(hfA, graph_ids, W1, b1, W2, b2, W3, b3, out);
}

// Round 8
// 757.933 us; speedup vs baseline: 1.0676x; 1.0207x over previous
//
#include <hip/hip_runtime.h>
#include <math.h>

#define N_NODES 50000
#define N_EDGES 800000
#define HID 64
#define N_GRAPHS 256
#define BN_EPS 1e-5f
#define GATE_EPS 1e-6f

static inline size_t align256(size_t x) { return (x + 255) & ~(size_t)255; }

// ---------------------------------------------------------------- utilities

__global__ void k_zero(int* __restrict__ p, int n) {
    for (int i = blockIdx.x * blockDim.x + threadIdx.x; i < n; i += gridDim.x * blockDim.x)
        p[i] = 0;
}

__global__ void k_deg(const int* __restrict__ dst, int* __restrict__ deg) {
    for (int i = blockIdx.x * blockDim.x + threadIdx.x; i < N_EDGES; i += gridDim.x * blockDim.x)
        atomicAdd(&deg[dst[i]], 1);
}

__global__ void k_norm(const int* __restrict__ deg, float* __restrict__ norm) {
    int i = blockIdx.x * blockDim.x + threadIdx.x;
    if (i < N_NODES) norm[i] = 1.0f / sqrtf(fmaxf((float)deg[i], 1.0f));
}

// exclusive scan of deg -> start (256/block, 2-level)
__global__ void k_scan1(const int* __restrict__ deg, int* __restrict__ start,
                        int* __restrict__ blksum) {
    __shared__ int s[256];
    int t = threadIdx.x;
    int i = blockIdx.x * 256 + t;
    int v = (i < N_NODES) ? deg[i] : 0;
    s[t] = v;
    __syncthreads();
    for (int off = 1; off < 256; off <<= 1) {
        int x = (t >= off) ? s[t - off] : 0;
        __syncthreads();
        s[t] += x;
        __syncthreads();
    }
    if (i < N_NODES) start[i] = s[t] - v;   // exclusive
    if (t == 255) blksum[blockIdx.x] = s[255];
}

__global__ void k_scan2(int* __restrict__ blksum, int nb) {
    __shared__ int s[256];
    int t = threadIdx.x;
    int v = (t < nb) ? blksum[t] : 0;
    s[t] = v;
    __syncthreads();
    for (int off = 1; off < 256; off <<= 1) {
        int x = (t >= off) ? s[t - off] : 0;
        __syncthreads();
        s[t] += x;
        __syncthreads();
    }
    if (t < nb) blksum[t] = s[t] - v;       // exclusive block offsets
}

__global__ void k_scan3(int* __restrict__ start, const int* __restrict__ blksum,
                        int* __restrict__ cursor) {
    int i = blockIdx.x * 256 + threadIdx.x;
    if (i < N_NODES) {
        int v = start[i] + blksum[blockIdx.x];
        start[i] = v;
        cursor[i] = v;
    }
    if (blockIdx.x == 0 && threadIdx.x == 0) start[N_NODES] = N_EDGES;
}

// scatter edges into dst-sorted order; meta = {src|etype<<24, norm[src] bits}
__global__ void k_scatter(const int* __restrict__ dst, const int* __restrict__ src,
                          const int* __restrict__ etype, const float* __restrict__ norm,
                          int* __restrict__ cursor, int2* __restrict__ edge_meta) {
    for (int i = blockIdx.x * blockDim.x + threadIdx.x; i < N_EDGES; i += gridDim.x * blockDim.x) {
        int p = atomicAdd(&cursor[dst[i]], 1);
        int s = src[i];
        edge_meta[p] = make_int2(s | (etype[i] << 24), __float_as_int(norm[s]));
    }
}

// node encoder: hf[n] = node_emb[h[n]]  (float4-vectorized, 16B/lane)
__global__ __launch_bounds__(256) void k_embed(const int* __restrict__ h,
                                               const float* __restrict__ node_emb,
                                               float4* __restrict__ hf4) {
    const int total4 = N_NODES * (HID / 4);
    for (int i = blockIdx.x * blockDim.x + threadIdx.x; i < total4; i += gridDim.x * blockDim.x) {
        int n = i >> 4, c4 = i & 15;
        hf4[i] = ((const float4*)node_emb)[h[n] * (HID / 4) + c4];
    }
}

// ------------------------------------------------------- fused edge kernel
// One wave per 4 NODES (lane == channel), 4 independent edge streams.
// r6 post-mortem: with default launch_bounds the compiler serialized the
// streams to hit VGPR=24 (occupancy-first scheduling) -> no MLP gain.
// This version: __launch_bounds__(256, 4) raises the VGPR budget to 128,
// and the loop is explicitly 1-deep software-pipelined: iteration it's
// meta/ef are preloaded at it-1; the body issues it's hf[s] gathers, then
// it+1's (address-affine) meta/ef loads, then consumes. Program order puts
// next-loads before the ef store, so alias analysis cannot sink them.
//
// MODE 0: ef_prev = emb table; no BN-apply; no ef write.
// MODE 1: ef_prev = emb table; apply BN_e(0); first ef write.
// MODE 2: ef_prev = global ef;  apply BN_e(prev); ef write.
// MODE 3: ef_prev = global ef;  apply BN_e(prev); NO write, no e-stats.
//
// All stream bookkeeping is wave-uniform; exhausted streams clamp their
// index (cache-hot re-reads) with stores/accumulation predicated off.
template <int MODE>
__global__ __launch_bounds__(256, 4) void k_edge(
    const int* __restrict__ start, const int2* __restrict__ edge_meta,
    const float* __restrict__ edge_emb,
    float* __restrict__ ef,
    const float* __restrict__ hf_old, const float* __restrict__ hf_new,
    const float* __restrict__ norm, float* __restrict__ h_new,
    const float* __restrict__ stats_prev, const float* __restrict__ gamma_prev,
    const float* __restrict__ beta_prev,
    float* __restrict__ stats_e_out, float* __restrict__ stats_h_out) {
    const int lane = threadIdx.x & 63;
    const int wid = __builtin_amdgcn_readfirstlane(blockIdx.x * 4 + (threadIdx.x >> 6));
    const int n0 = wid * 4;   // this wave's 4 consecutive nodes

    __shared__ float s_emb[4 * HID];
    if (MODE <= 1) {
        for (int i = threadIdx.x; i < 4 * HID; i += blockDim.x) s_emb[i] = edge_emb[i];
        __syncthreads();
    }
    float a_prev = 0.f, c_prev = 0.f;
    if (MODE >= 1) {
        float s1 = stats_prev[lane], s2 = stats_prev[HID + lane];
        float mu = s1 * (1.0f / N_EDGES);
        float var = s2 * (1.0f / N_EDGES) - mu * mu;
        float rstd = 1.0f / sqrtf(var + BN_EPS);
        a_prev = gamma_prev[lane] * rstd;
        c_prev = beta_prev[lane] - mu * a_prev;
    }

    // per-stream setup (k fully unrolled -> static indexing, regs not scratch)
    int jbeg[4], len[4];
    float hnn[4], hon[4], amsg[4], aden[4];
    int maxlen = 0;
#pragma unroll
    for (int k = 0; k < 4; ++k) {
        jbeg[k] = start[n0 + k];
        len[k] = start[n0 + k + 1] - jbeg[k];
        maxlen = max(maxlen, len[k]);
        hnn[k] = hf_new[(n0 + k) * HID + lane];
        hon[k] = (MODE >= 1) ? hf_old[(n0 + k) * HID + lane] : 0.f;
        amsg[k] = 0.f;
        aden[k] = 0.f;
    }

    // clamped slot index for stream k at iteration it (always in-bounds)
    auto eidx = [&](int k, int it) {
        int itc = min(it, max(len[k] - 1, 0));
        return min(jbeg[k] + itc, N_EDGES - 1);
    };

    float sum_e = 0.f, sumsq_e = 0.f, sum_h = 0.f, sumsq_h = 0.f;
    if (maxlen > 0) {
        // ---- prologue: meta/ef for iteration 0
        int2 mt[4];
        float efp[4];
#pragma unroll
        for (int k = 0; k < 4; ++k) {
            const int j0 = eidx(k, 0);
            mt[k] = edge_meta[j0];
            efp[k] = (MODE >= 2) ? ef[(size_t)j0 * HID + lane] : 0.f;
        }
        for (int it = 0; it < maxlen; ++it) {
            // ---- issue current iteration's gathers (dependent on mt)
            int sg[4];
            float hs[4], ho[4];
#pragma unroll
            for (int k = 0; k < 4; ++k) {
                sg[k] = mt[k].x & 0xFFFFFF;
                hs[k] = hf_new[sg[k] * HID + lane];
                ho[k] = (MODE >= 1) ? hf_old[sg[k] * HID + lane] : 0.f;
            }
            // ---- issue next iteration's meta/ef (independent, affine addr)
            const int itn = (it + 1 < maxlen) ? it + 1 : it;
            int2 mtn[4];
            float efn[4];
#pragma unroll
            for (int k = 0; k < 4; ++k) {
                const int jn = eidx(k, itn);
                mtn[k] = edge_meta[jn];
                efn[k] = (MODE >= 2) ? ef[(size_t)jn * HID + lane] : 0.f;
            }
            // ---- consume current iteration
#pragma unroll
            for (int k = 0; k < 4; ++k) {
                const bool act = it < len[k];                  // wave-uniform
                float efv;
                if (MODE == 0) {
                    efv = s_emb[(mt[k].x >> 24) * HID + lane];
                } else if (MODE == 1) {
                    const float ef0 = s_emb[(mt[k].x >> 24) * HID + lane];
                    const float ep = ho[k] + hon[k] + ef0;
                    efv = ef0 + fmaxf(a_prev * ep + c_prev, 0.f);
                    if (act) ef[(size_t)(jbeg[k] + it) * HID + lane] = efv;
                } else {
                    const float ep = ho[k] + hon[k] + efp[k];
                    efv = efp[k] + fmaxf(a_prev * ep + c_prev, 0.f);
                    if (MODE == 2) {
                        if (act) ef[(size_t)(jbeg[k] + it) * HID + lane] = efv;
                    }
                }
                const float en = hs[k] + hnn[k] + efv;
                const float sgm = 1.0f / (1.0f + __expf(-en));
                if (act) {
                    amsg[k] += sgm * hs[k] * __int_as_float(mt[k].y);
                    aden[k] += sgm;
                    if (MODE != 3) { sum_e += en; sumsq_e += en * en; }
                }
            }
            // ---- rotate pipeline
#pragma unroll
            for (int k = 0; k < 4; ++k) { mt[k] = mtn[k]; efp[k] = efn[k]; }
        }
    }

#pragma unroll
    for (int k = 0; k < 4; ++k) {
        const float nm = norm[n0 + k];
        const float hval = (hnn[k] * nm + amsg[k] / (aden[k] + GATE_EPS)) * nm;
        h_new[(n0 + k) * HID + lane] = hval;
        sum_h += hval;
        sumsq_h += hval * hval;
    }

    __shared__ float sred[4][256];
    sred[0][threadIdx.x] = sum_e;
    sred[1][threadIdx.x] = sumsq_e;
    sred[2][threadIdx.x] = sum_h;
    sred[3][threadIdx.x] = sumsq_h;
    __syncthreads();
    if (threadIdx.x < 64) {
        const int t = threadIdx.x;
        if (MODE != 3) {
            float t1 = sred[0][t] + sred[0][t + 64] + sred[0][t + 128] + sred[0][t + 192];
            float t2 = sred[1][t] + sred[1][t + 64] + sred[1][t + 128] + sred[1][t + 192];
            atomicAdd(&stats_e_out[t], t1);
            atomicAdd(&stats_e_out[HID + t], t2);
        }
        float t3 = sred[2][t] + sred[2][t + 64] + sred[2][t + 128] + sred[2][t + 192];
        float t4 = sred[3][t] + sred[3][t + 64] + sred[3][t + 128] + sred[3][t + 192];
        atomicAdd(&stats_h_out[t], t3);
        atomicAdd(&stats_h_out[HID + t], t4);
    }
}

// ------------------------------------------------------------- node update
// hf_out = hf_in + relu(bn_h(h_new)), float4-vectorized (16B/lane).
__global__ __launch_bounds__(256) void k_hupd(
    const float4* __restrict__ hf_in, const float4* __restrict__ h_new,
    const float* __restrict__ stats, const float* __restrict__ gamma,
    const float* __restrict__ beta, float4* __restrict__ hf_out) {
    const int tid = blockIdx.x * blockDim.x + threadIdx.x;
    const int c0 = (tid & 15) * 4;
    float a[4], c[4];
#pragma unroll
    for (int k = 0; k < 4; ++k) {
        int ch = c0 + k;
        float mu = stats[ch] * (1.0f / N_NODES);
        float var = stats[HID + ch] * (1.0f / N_NODES) - mu * mu;
        float rstd = 1.0f / sqrtf(var + BN_EPS);
        a[k] = gamma[ch] * rstd;
        c[k] = beta[ch] - mu * a[k];
    }
    const int total4 = N_NODES * (HID / 4);
    for (int i = tid; i < total4; i += gridDim.x * blockDim.x) {
        float4 hi = hf_in[i], hn = h_new[i], o;
        o.x = hi.x + fmaxf(a[0] * hn.x + c[0], 0.f);
        o.y = hi.y + fmaxf(a[1] * hn.y + c[1], 0.f);
        o.z = hi.z + fmaxf(a[2] * hn.z + c[2], 0.f);
        o.w = hi.w + fmaxf(a[3] * hn.w + c[3], 0.f);
        hf_out[i] = o;
    }
}

// --------------------------------------------- fused mean-pool + MLP head
// graph_ids is sorted: one block per graph, binary-search the node range.
__global__ __launch_bounds__(256) void k_poolmlp(
    const float* __restrict__ hf, const int* __restrict__ graph_ids,
    const float* __restrict__ W1, const float* __restrict__ b1,
    const float* __restrict__ W2, const float* __restrict__ b2,
    const float* __restrict__ W3, const float* __restrict__ b3,
    float* __restrict__ out) {
    const int g = blockIdx.x;
    int a = 0, b = N_NODES;
    while (a < b) { int m = (a + b) >> 1; if (graph_ids[m] < g) a = m + 1; else b = m; }
    const int lo = a;
    b = N_NODES;
    while (a < b) { int m = (a + b) >> 1; if (graph_ids[m] < g + 1) a = m + 1; else b = m; }
    const int hi = a;

    const int lane = threadIdx.x & 63, w = threadIdx.x >> 6;
    float acc = 0.f;
    for (int n = lo + w; n < hi; n += 4) acc += hf[n * HID + lane];
    __shared__ float sred[256];
    __shared__ float sh[64], sx1[32], sx2[16];
    sred[threadIdx.x] = acc;
    __syncthreads();
    if (threadIdx.x < 64) {
        float tot = sred[lane] + sred[lane + 64] + sred[lane + 128] + sred[lane + 192];
        sh[lane] = tot / fmaxf((float)(hi - lo), 1.0f);
    }
    __syncthreads();
    const int t = threadIdx.x;
    if (t < 32) {
        float s = b1[t];
        for (int c = 0; c < 64; ++c) s += sh[c] * W1[c * 32 + t];
        sx1[t] = fmaxf(s, 0.f);
    }
    __syncthreads();
    if (t < 16) {
        float s = b2[t];
        for (int k = 0; k < 32; ++k) s += sx1[k] * W2[k * 16 + t];
        sx2[t] = fmaxf(s, 0.f);
    }
    __syncthreads();
    if (t == 0) {
        float s = b3[0];
        for (int k = 0; k < 16; ++k) s += sx2[k] * W3[k];
        out[g] = s;
    }
}

// -------------------------------------------------------------------- launch

extern "C" void kernel_launch(void* const* d_in, const int* in_sizes, int n_in,
                              void* d_out, int out_size, void* d_ws, size_t ws_size,
                              hipStream_t stream) {
    const int* h_idx      = (const int*)d_in[0];
    const int* e_idx      = (const int*)d_in[1];
    const int* src        = (const int*)d_in[2];
    const int* dst        = (const int*)d_in[3];
    const int* graph_ids  = (const int*)d_in[4];
    const float* node_emb = (const float*)d_in[5];
    const float* edge_emb = (const float*)d_in[6];
    const float* bnh_g    = (const float*)d_in[7];
    const float* bnh_b    = (const float*)d_in[8];
    const float* bne_g    = (const float*)d_in[9];
    const float* bne_b    = (const float*)d_in[10];
    const float* W1       = (const float*)d_in[11];
    const float* b1       = (const float*)d_in[12];
    const float* W2       = (const float*)d_in[13];
    const float* b2       = (const float*)d_in[14];
    const float* W3       = (const float*)d_in[15];
    const float* b3       = (const float*)d_in[16];
    float* out = (float*)d_out;

    // ---- workspace layout (~262 MB)
    char* w = (char*)d_ws;
    size_t off = 0;
    auto alloc = [&](size_t bytes) -> void* {
        void* p = w + off;
        off = align256(off + bytes);
        return p;
    };
    float* ef        = (float*)alloc((size_t)N_EDGES * HID * 4);   // sorted-slot order
    float* hfA       = (float*)alloc((size_t)N_NODES * HID * 4);
    float* hfB       = (float*)alloc((size_t)N_NODES * HID * 4);
    float* h_new     = (float*)alloc((size_t)N_NODES * HID * 4);
    float* norm      = (float*)alloc((size_t)N_NODES * 4);
    int2*  edge_meta = (int2*)alloc((size_t)N_EDGES * 8);
    int*   start     = (int*)alloc((size_t)(N_NODES + 1) * 4);
    int*   cursor    = (int*)alloc((size_t)N_NODES * 4);
    int*   blksum    = (int*)alloc(256 * 4);
    // zero-initialized region (contiguous)
    size_t zoff = off;
    int*   deg       = (int*)alloc((size_t)N_NODES * 4);
    float* stats_e   = (float*)alloc(4 * 2 * HID * 4);
    float* stats_h   = (float*)alloc(4 * 2 * HID * 4);
    int zero_elems = (int)((off - zoff) / 4);
    int* zbase = (int*)(w + zoff);

    const int NB_SCAN = (N_NODES + 255) / 256;   // 196

    // ---- preprocessing
    k_zero<<<64, 256, 0, stream>>>(zbase, zero_elems);
    k_deg<<<1024, 256, 0, stream>>>(dst, deg);
    k_norm<<<NB_SCAN, 256, 0, stream>>>(deg, norm);
    k_scan1<<<NB_SCAN, 256, 0, stream>>>(deg, start, blksum);
    k_scan2<<<1, 256, 0, stream>>>(blksum, NB_SCAN);
    k_scan3<<<NB_SCAN, 256, 0, stream>>>(start, blksum, cursor);
    k_scatter<<<1024, 256, 0, stream>>>(dst, src, e_idx, norm, cursor, edge_meta);
    k_embed<<<512, 256, 0, stream>>>(h_idx, node_emb, (float4*)hfA);

    const int EG = N_NODES / 16;   // 3125 blocks: 4 waves x 4 nodes each, exact
    const int NG = 512;            // node-kernel blocks

    // ---- layer 0 (ef_prev from emb table, no BN-apply)
    k_edge<0><<<EG, 256, 0, stream>>>(start, edge_meta, edge_emb, ef,
        nullptr, hfA, norm, h_new, nullptr, nullptr, nullptr,
        stats_e + 0 * 128, stats_h + 0 * 128);
    k_hupd<<<NG, 256, 0, stream>>>((const float4*)hfA, (const float4*)h_new,
        stats_h + 0 * 128, bnh_g + 0 * HID, bnh_b + 0 * HID, (float4*)hfB);

    // ---- layer 1 (ef_prev from emb table; apply BN_e(0); first ef write)
    k_edge<1><<<EG, 256, 0, stream>>>(start, edge_meta, edge_emb, ef,
        hfA, hfB, norm, h_new, stats_e + 0 * 128, bne_g + 0 * HID, bne_b + 0 * HID,
        stats_e + 1 * 128, stats_h + 1 * 128);
    k_hupd<<<NG, 256, 0, stream>>>((const float4*)hfB, (const float4*)h_new,
        stats_h + 1 * 128, bnh_g + 1 * HID, bnh_b + 1 * HID, (float4*)hfA);

    // ---- layer 2 (ef read+write)
    k_edge<2><<<EG, 256, 0, stream>>>(start, edge_meta, edge_emb, ef,
        hfB, hfA, norm, h_new, stats_e + 1 * 128, bne_g + 1 * HID, bne_b + 1 * HID,
        stats_e + 2 * 128, stats_h + 2 * 128);
    k_hupd<<<NG, 256, 0, stream>>>((const float4*)hfA, (const float4*)h_new,
        stats_h + 2 * 128, bnh_g + 2 * HID, bnh_b + 2 * HID, (float4*)hfB);

    // ---- layer 3 (ef read only; e-side outputs dead)
    k_edge<3><<<EG, 256, 0, stream>>>(start, edge_meta, edge_emb, ef,
        hfA, hfB, norm, h_new, stats_e + 2 * 128, bne_g + 2 * HID, bne_b + 2 * HID,
        stats_e + 3 * 128, stats_h + 3 * 128);
    k_hupd<<<NG, 256, 0, stream>>>((const float4*)hfB, (const float4*)h_new,
        stats_h + 3 * 128, bnh_g + 3 * HID, bnh_b + 3 * HID, (float4*)hfA);

    // ---- fused mean-pool + MLP readout
    k_poolmlp<<<N_GRAPHS, 256, 0, stream>>>(hfA, graph_ids, W1, b1, W2, b2, W3, b3, out);
}